// Round 4
// baseline (353.430 us; speedup 1.0000x reference)
//
#include <hip/hip_runtime.h>
#include <hip/hip_bf16.h>

// Problem constants (reference: B,K,N,F,H = 20000,10,100000,256,128)
constexpr int B_ = 20000;
constexpr int K_ = 10;
constexpr int N_ = 100000;
constexpr int F_ = 256;
constexpr int H_ = 128;
constexpr int RW = 3 * H_;  // interleaved qkv row width (384 ushorts = 768 B)

typedef __attribute__((ext_vector_type(8))) short bf16x8;
typedef __attribute__((ext_vector_type(4))) float f32x4;
typedef __attribute__((ext_vector_type(16))) float f32x16;
typedef __attribute__((ext_vector_type(4))) unsigned short ushort4v;

__device__ __forceinline__ unsigned short f2bf(float x) {
  // round-to-nearest-even fp32 -> bf16
  unsigned int u = __builtin_bit_cast(unsigned int, x);
  unsigned int r = u + 0x7fffu + ((u >> 16) & 1u);
  return (unsigned short)(r >> 16);
}

__device__ __forceinline__ float bf2f(unsigned int u16) {
  return __builtin_bit_cast(float, u16 << 16);
}

__device__ __forceinline__ float fast_tanh(float x) {
  float e = __expf(2.0f * x);
  return 1.0f - 2.0f * __builtin_amdgcn_rcpf(e + 1.0f);
}

// ---------------------------------------------------------------------------
// Prep: bf16-transpose the six weight matrices.
// wat[p][h][k] = Wa_p[k][h]  (3 x 128 x 256)
// wbt[p][h][k] = Wb_p[k][h]  (3 x 128 x 128)
// ---------------------------------------------------------------------------
__global__ __launch_bounds__(256) void prep_kernel(
    const float* __restrict__ W1a, const float* __restrict__ W1b,
    const float* __restrict__ W2a, const float* __restrict__ W2b,
    const float* __restrict__ W3a, const float* __restrict__ W3b,
    unsigned short* __restrict__ wat, unsigned short* __restrict__ wbt) {
  const float* Wa[3] = {W1a, W2a, W3a};
  const float* Wb[3] = {W1b, W2b, W3b};
  int g = blockIdx.x * 256 + threadIdx.x;
  if (g < 3 * F_ * H_) {
    int p = g >> 15;
    int r = g & (F_ * H_ - 1);
    int h = r >> 8;
    int k = r & 255;
    wat[g] = f2bf(Wa[p][k * H_ + h]);
  } else {
    int g2 = g - 3 * F_ * H_;
    int p = g2 >> 14;
    int r = g2 & (H_ * H_ - 1);
    int h = r >> 7;
    int k = r & 127;
    wbt[g2] = f2bf(Wb[p][k * H_ + h]);
  }
}

// ---------------------------------------------------------------------------
// Pass 1: u_p = tanh(E @ Wa_p), written into qkvI[n][p*128 + col] (bf16).
// Block 256 = 4 waves, MT=64 rows. Wave w owns cols [32w,32w+32) -> weights
// read once per block. mfma_32x32x16_bf16, ONE barrier per block (staging).
// ---------------------------------------------------------------------------
constexpr int MT = 64;
constexpr int XS = F_ + 8;  // 264 ushorts = 528 B row stride

__global__ __launch_bounds__(256) void proj1_kernel(
    const float* __restrict__ E,
    const unsigned short* __restrict__ wat,
    unsigned short* __restrict__ qkvI) {
  __shared__ unsigned short xs[MT * XS];  // 33.8 KB

  const int tid = threadIdx.x;
  const int lane = tid & 63;
  const int w = tid >> 6;
  const int m = lane & 31;   // MFMA row/col index within 32
  const int hf = lane >> 5;  // k-half (0/1)
  const int row0 = blockIdx.x * MT;

  // ---- stage X tile (fp32 -> bf16), coalesced, zero-pad OOB rows
  {
    const float4* Eg = (const float4*)E;
#pragma unroll
    for (int it = 0; it < 16; ++it) {
      int i = tid + 256 * it;
      int r = i >> 6;
      int c4 = i & 63;
      float4 v = make_float4(0.f, 0.f, 0.f, 0.f);
      if (row0 + r < N_) v = Eg[(size_t)(row0 + r) * (F_ / 4) + c4];
      ushort4v o;
      o.x = f2bf(v.x); o.y = f2bf(v.y); o.z = f2bf(v.z); o.w = f2bf(v.w);
      *(ushort4v*)&xs[r * XS + c4 * 4] = o;
    }
  }
  __syncthreads();

  for (int p = 0; p < 3; ++p) {
    const unsigned short* __restrict__ wap = wat + p * (F_ * H_);

    f32x16 acc0 = (f32x16)0.0f;
    f32x16 acc1 = (f32x16)0.0f;

#pragma unroll
    for (int k = 0; k < 16; ++k) {  // K = 256, 16 per step
      const int koff = k * 16 + hf * 8;
      bf16x8 b = *(const bf16x8*)&wap[(w * 32 + m) * F_ + koff];
      bf16x8 a0 = *(const bf16x8*)&xs[m * XS + koff];
      bf16x8 a1 = *(const bf16x8*)&xs[(32 + m) * XS + koff];
      acc0 = __builtin_amdgcn_mfma_f32_32x32x16_bf16(a0, b, acc0, 0, 0, 0);
      acc1 = __builtin_amdgcn_mfma_f32_32x32x16_bf16(a1, b, acc1, 0, 0, 0);
    }

    // C/D layout (32x32): col = lane&31, row = (reg&3) + 8*(reg>>2) + 4*(lane>>5)
    const int col = p * H_ + w * 32 + m;
#pragma unroll
    for (int reg = 0; reg < 16; ++reg) {
      int rr = (reg & 3) + 8 * (reg >> 2) + 4 * hf;
      int n0 = row0 + rr;
      int n1 = row0 + 32 + rr;
      if (n0 < N_) qkvI[(size_t)n0 * RW + col] = f2bf(fast_tanh(acc0[reg]));
      if (n1 < N_) qkvI[(size_t)n1 * RW + col] = f2bf(fast_tanh(acc1[reg]));
    }
  }
}

// ---------------------------------------------------------------------------
// Pass 2: qkv_p = u_p @ Wb_p, IN PLACE in qkvI. One wave owns 16 rows x all
// 128 cols -> no inter-wave hazard, no LDS, no barriers. Store->load ordering
// within the wave is enforced by register dependence through the MFMA chain.
// ---------------------------------------------------------------------------
__global__ __launch_bounds__(256) void proj2_kernel(
    const unsigned short* __restrict__ wbt,
    unsigned short* __restrict__ qkvI) {
  const int tid = threadIdx.x;
  const int lane = tid & 63;
  const int gw = (blockIdx.x * 256 + tid) >> 6;  // global wave id
  const int row0 = gw * 16;
  if (row0 >= N_) return;
  const int l15 = lane & 15;
  const int q4 = lane >> 4;

  for (int p = 0; p < 3; ++p) {
    const unsigned short* __restrict__ wbp = wbt + p * (H_ * H_);

    f32x4 acc[8];
#pragma unroll
    for (int c = 0; c < 8; ++c) acc[c] = (f32x4)0.0f;

    const size_t abase = (size_t)(row0 + l15) * RW + p * H_;
#pragma unroll
    for (int k = 0; k < 4; ++k) {  // K = 128, 32 per step
      const int koff = k * 32 + q4 * 8;
      bf16x8 a = *(const bf16x8*)&qkvI[abase + koff];
#pragma unroll
      for (int c = 0; c < 8; ++c) {
        bf16x8 b = *(const bf16x8*)&wbp[(c * 16 + l15) * H_ + koff];
        acc[c] = __builtin_amdgcn_mfma_f32_16x16x32_bf16(a, b, acc[c], 0, 0, 0);
      }
    }

    // C/D layout (16x16): col = lane&15, row = (lane>>4)*4 + r
#pragma unroll
    for (int c = 0; c < 8; ++c)
#pragma unroll
      for (int r = 0; r < 4; ++r) {
        int n = row0 + q4 * 4 + r;
        qkvI[(size_t)n * RW + p * H_ + c * 16 + l15] = f2bf(acc[c][r]);
      }
  }
}

// ---------------------------------------------------------------------------
// Phase 2: one WAVE per batch node, gathering from the INTERLEAVED qkvI
// (768 B contiguous per neighbor). No LDS, no barriers.
// ---------------------------------------------------------------------------
__global__ __launch_bounds__(256) void agg_kernel(
    const int* __restrict__ nbr,
    const unsigned short* __restrict__ qkvI,
    float* __restrict__ out) {
  const int lane = threadIdx.x & 63;
  const int wv = threadIdx.x >> 6;
  const int b = blockIdx.x * 4 + wv;
  const int l15 = lane & 15;
  const int kg = lane >> 4;

  // neighbor id for this lane's row slot (clamp rows 10..15; masked later)
  const int ni = nbr[b * K_ + (l15 < K_ ? l15 : 0)];
  const size_t nbase = (size_t)ni * RW;

  // scores[i][j] = q_i . k_j (A = Q rows, B = K rows; same lane pattern)
  f32x4 sc = (f32x4)0.0f;
#pragma unroll
  for (int k = 0; k < 4; ++k) {
    const int off = k * 32 + kg * 8;
    bf16x8 qf = *(const bf16x8*)&qkvI[nbase + off];
    bf16x8 kf = *(const bf16x8*)&qkvI[nbase + H_ + off];
    sc = __builtin_amdgcn_mfma_f32_16x16x32_bf16(qf, kf, sc, 0, 0, 0);
  }
  // C layout: row i = kg*4 + r, col j = l15

  if (l15 >= K_) {
#pragma unroll
    for (int r = 0; r < 4; ++r) sc[r] = -3.0e38f;
  }

  // row-wise softmax over cols (width-16 shuffles)
  float mx[4], e[4], sm[4];
#pragma unroll
  for (int r = 0; r < 4; ++r) mx[r] = sc[r];
#pragma unroll
  for (int st = 1; st < 16; st <<= 1)
#pragma unroll
    for (int r = 0; r < 4; ++r) mx[r] = fmaxf(mx[r], __shfl_xor(mx[r], st, 16));
#pragma unroll
  for (int r = 0; r < 4; ++r) { e[r] = __expf(sc[r] - mx[r]); sm[r] = e[r]; }
#pragma unroll
  for (int st = 1; st < 16; st <<= 1)
#pragma unroll
    for (int r = 0; r < 4; ++r) sm[r] += __shfl_xor(sm[r], st, 16);

  // att + zero invalid rows, then column sums over i
  float cs = 0.0f;
#pragma unroll
  for (int r = 0; r < 4; ++r) {
    float a = e[r] * __builtin_amdgcn_rcpf(sm[r]);
    if (kg * 4 + r >= K_) a = 0.0f;
    cs += a;
  }
  cs += __shfl_xor(cs, 16, 64);
  cs += __shfl_xor(cs, 32, 64);
  // lane holds colsum[j = l15] (j >= 10 hold 0)

  // out[b,d] = sum_j colsum[j] * V[j][d]; lane handles d = 2*lane, 2*lane+1
  float o0 = 0.0f, o1 = 0.0f;
#pragma unroll
  for (int j = 0; j < K_; ++j) {
    const float cj = __shfl(cs, j, 64);
    const int nj = __shfl(ni, j, 64);
    const unsigned int v2 =
        *(const unsigned int*)&qkvI[(size_t)nj * RW + 2 * H_ + 2 * lane];
    o0 = fmaf(cj, bf2f(v2 & 0xffffu), o0);
    o1 = fmaf(cj, bf2f(v2 >> 16), o1);
  }
  *(float2*)&out[(size_t)b * H_ + 2 * lane] = make_float2(o0, o1);
}

extern "C" void kernel_launch(void* const* d_in, const int* in_sizes, int n_in,
                              void* d_out, int out_size, void* d_ws, size_t ws_size,
                              hipStream_t stream) {
  const int* nbr = (const int*)d_in[0];
  const float* E = (const float*)d_in[1];
  const float* W1a = (const float*)d_in[2];
  const float* W1b = (const float*)d_in[3];
  const float* W2a = (const float*)d_in[4];
  const float* W2b = (const float*)d_in[5];
  const float* W3a = (const float*)d_in[6];
  const float* W3b = (const float*)d_in[7];
  float* out = (float*)d_out;

  // workspace: qkvI [N][384] bf16 interleaved q|k|v = 76.8 MB, then weights
  unsigned short* qkvI = (unsigned short*)d_ws;
  unsigned short* wat = qkvI + (size_t)N_ * RW;
  unsigned short* wbt = wat + (size_t)3 * F_ * H_;

  prep_kernel<<<(3 * F_ * H_ + 3 * H_ * H_) / 256, 256, 0, stream>>>(
      W1a, W1b, W2a, W2b, W3a, W3b, wat, wbt);
  proj1_kernel<<<(N_ + MT - 1) / MT, 256, 0, stream>>>(E, wat, qkvI);
  proj2_kernel<<<(N_ / 16 + 3) / 4, 256, 0, stream>>>(wbt, qkvI);
  agg_kernel<<<B_ / 4, 256, 0, stream>>>(nbr, qkvI, out);
}

// Round 5
// 339.450 us; speedup vs baseline: 1.0412x; 1.0412x over previous
//
#include <hip/hip_runtime.h>
#include <hip/hip_bf16.h>

// Problem constants (reference: B,K,N,F,H = 20000,10,100000,256,128)
constexpr int B_ = 20000;
constexpr int K_ = 10;
constexpr int N_ = 100000;
constexpr int F_ = 256;
constexpr int H_ = 128;
constexpr int RW = 3 * H_;  // interleaved qkv row width (384 ushorts = 768 B)

typedef __attribute__((ext_vector_type(8))) short bf16x8;
typedef __attribute__((ext_vector_type(4))) float f32x4;
typedef __attribute__((ext_vector_type(4))) unsigned int uint4v;
typedef __attribute__((ext_vector_type(4))) unsigned short ushort4v;

__device__ __forceinline__ unsigned short f2bf(float x) {
  unsigned int u = __builtin_bit_cast(unsigned int, x);
  unsigned int r = u + 0x7fffu + ((u >> 16) & 1u);
  return (unsigned short)(r >> 16);
}

__device__ __forceinline__ unsigned int packbf(float a, float b) {
  return (unsigned int)f2bf(a) | ((unsigned int)f2bf(b) << 16);
}

__device__ __forceinline__ float bf2f(unsigned int u16) {
  return __builtin_bit_cast(float, u16 << 16);
}

__device__ __forceinline__ float fast_tanh(float x) {
  float e = __expf(2.0f * x);
  return 1.0f - 2.0f * __builtin_amdgcn_rcpf(e + 1.0f);
}

// ---------------------------------------------------------------------------
// Prep: weights -> fragment-major bf16 layout.
// wat2: chunks (p, ks∈8, c∈8), each 512 bf16 = one 16x16x32 A-fragment of
//   Wa_p^T: elem(lane,j) = Wa_p[f = 32ks+8*(lane>>4)+j][h = 16c+(lane&15)]
// wbt2: chunks (p, c2∈8, ks2∈4): elem(lane,j) = Wb_p[h1=32ks2+8*(lane>>4)+j][h2=16c2+(lane&15)]
// Frag loads in proj are then lane*16B contiguous (perfect coalescing).
// ---------------------------------------------------------------------------
__global__ __launch_bounds__(256) void prep_kernel(
    const float* __restrict__ W1a, const float* __restrict__ W1b,
    const float* __restrict__ W2a, const float* __restrict__ W2b,
    const float* __restrict__ W3a, const float* __restrict__ W3b,
    unsigned short* __restrict__ wat2, unsigned short* __restrict__ wbt2) {
  const float* Wa[3] = {W1a, W2a, W3a};
  const float* Wb[3] = {W1b, W2b, W3b};
  int g = blockIdx.x * 256 + threadIdx.x;
  if (g < 3 * 64 * 512) {  // 98304 wa elems
    int chunk = g >> 9;
    int e = g & 511;
    int lane = e >> 3, j = e & 7;
    int c = chunk & 7;
    int ks = (chunk >> 3) & 7;
    int p = chunk >> 6;
    int k = 32 * ks + 8 * (lane >> 4) + j;
    int h = 16 * c + (lane & 15);
    wat2[g] = f2bf(Wa[p][k * H_ + h]);
  } else {
    int g2 = g - 3 * 64 * 512;
    int chunk = g2 >> 9;
    int e = g2 & 511;
    int lane = e >> 3, j = e & 7;
    int ks2 = chunk & 3;
    int c2 = (chunk >> 2) & 7;
    int p = chunk >> 5;
    int k = 32 * ks2 + 8 * (lane >> 4) + j;
    int h2 = 16 * c2 + (lane & 15);
    wbt2[g2] = f2bf(Wb[p][k * H_ + h2]);
  }
}

// ---------------------------------------------------------------------------
// Fused projections, transposed compute, zero LDS / zero barriers.
// One wave owns 32 nodes (2 groups of 16) x all 128 output cols x all 3 projs.
//  - X^T fragments (E rows) read ONCE into 64 VGPRs, reused by all 24 GEMM tiles.
//  - Layer1: U^T tile = mfma(A=Wa^T frag, B=X^T frag); tanh+pack in regs.
//  - Layer1->Layer2 operand transpose via __shfl (no LDS round-trip):
//      bfrag[ks2].dword[d] <- pk[2ks2+(q>>1)][d&1] from lane 16*(2(q&1)+(d>>1))+l15
//  - Layer2: P^T = mfma(A=Wb^T frag, B=tanh frag); pack 4 f32 -> 8B store.
// ---------------------------------------------------------------------------
__global__ __launch_bounds__(256, 3) void proj_kernel(
    const float* __restrict__ E,
    const unsigned short* __restrict__ wat2,
    const unsigned short* __restrict__ wbt2,
    unsigned short* __restrict__ qkvI) {
  const int lane = threadIdx.x & 63;
  const int gw = (blockIdx.x * 256 + threadIdx.x) >> 6;  // global wave id
  const int node0 = gw * 32;
  if (node0 >= N_) return;
  const int l15 = lane & 15;
  const int q = lane >> 4;

  // ---- gather X^T fragments: lane reads 32B (8 floats) of its node's E row
  uint4v xf[2][8];
#pragma unroll
  for (int g = 0; g < 2; ++g) {
    const float* rowp = E + (size_t)(node0 + 16 * g + l15) * F_;
#pragma unroll
    for (int ks = 0; ks < 8; ++ks) {
      float4 v0 = *(const float4*)(rowp + ks * 32 + q * 8);
      float4 v1 = *(const float4*)(rowp + ks * 32 + q * 8 + 4);
      uint4v u;
      u.x = packbf(v0.x, v0.y);
      u.y = packbf(v0.z, v0.w);
      u.z = packbf(v1.x, v1.y);
      u.w = packbf(v1.z, v1.w);
      xf[g][ks] = u;
    }
  }

  for (int p = 0; p < 3; ++p) {
    const unsigned short* __restrict__ wa = wat2 + p * (64 * 512);
    const unsigned short* __restrict__ wb = wbt2 + p * (32 * 512);

    // ---- layer 1: 8 h-tiles, K=256. pk[g][c][e]: packed tanh(U^T) pairs.
    unsigned int pk[2][8][2];
#pragma unroll
    for (int c = 0; c < 8; ++c) {
      f32x4 a0 = (f32x4)0.0f, a1 = (f32x4)0.0f;
#pragma unroll
      for (int ks = 0; ks < 8; ++ks) {
        bf16x8 af = *(const bf16x8*)&wa[(ks * 8 + c) * 512 + lane * 8];
        a0 = __builtin_amdgcn_mfma_f32_16x16x32_bf16(
            af, __builtin_bit_cast(bf16x8, xf[0][ks]), a0, 0, 0, 0);
        a1 = __builtin_amdgcn_mfma_f32_16x16x32_bf16(
            af, __builtin_bit_cast(bf16x8, xf[1][ks]), a1, 0, 0, 0);
      }
      // C layout: row h1 = 16c + 4q + r, col = node l15
      pk[0][c][0] = packbf(fast_tanh(a0[0]), fast_tanh(a0[1]));
      pk[0][c][1] = packbf(fast_tanh(a0[2]), fast_tanh(a0[3]));
      pk[1][c][0] = packbf(fast_tanh(a1[0]), fast_tanh(a1[1]));
      pk[1][c][1] = packbf(fast_tanh(a1[2]), fast_tanh(a1[3]));
    }

    // ---- in-register transpose to layer-2 B-fragments
    // bf[g][ks2][d] holds T[h1 = 32ks2 + 8q + 2d, +1][node l15]
    unsigned int bfr[2][4][4];
#pragma unroll
    for (int ks2 = 0; ks2 < 4; ++ks2)
#pragma unroll
      for (int d = 0; d < 4; ++d) {
        const int sl = 16 * (2 * (q & 1) + (d >> 1)) + l15;
#pragma unroll
        for (int g = 0; g < 2; ++g) {
          unsigned int lo =
              (unsigned int)__shfl((int)pk[g][2 * ks2][d & 1], sl, 64);
          unsigned int hi =
              (unsigned int)__shfl((int)pk[g][2 * ks2 + 1][d & 1], sl, 64);
          bfr[g][ks2][d] = (q >> 1) ? hi : lo;
        }
      }

    // ---- layer 2: 8 h2-tiles, K=128; store packed 8B per lane
#pragma unroll
    for (int c2 = 0; c2 < 8; ++c2) {
      f32x4 a0 = (f32x4)0.0f, a1 = (f32x4)0.0f;
#pragma unroll
      for (int ks2 = 0; ks2 < 4; ++ks2) {
        bf16x8 af = *(const bf16x8*)&wb[(c2 * 4 + ks2) * 512 + lane * 8];
        uint4v b0 = {bfr[0][ks2][0], bfr[0][ks2][1], bfr[0][ks2][2], bfr[0][ks2][3]};
        uint4v b1 = {bfr[1][ks2][0], bfr[1][ks2][1], bfr[1][ks2][2], bfr[1][ks2][3]};
        a0 = __builtin_amdgcn_mfma_f32_16x16x32_bf16(
            af, __builtin_bit_cast(bf16x8, b0), a0, 0, 0, 0);
        a1 = __builtin_amdgcn_mfma_f32_16x16x32_bf16(
            af, __builtin_bit_cast(bf16x8, b1), a1, 0, 0, 0);
      }
      // C layout: row h2 = 16c2 + 4q + r, col = node l15 -> 8B store per lane
#pragma unroll
      for (int g = 0; g < 2; ++g) {
        const f32x4 acc = g ? a1 : a0;
        ushort4v o;
        o.x = f2bf(acc[0]); o.y = f2bf(acc[1]);
        o.z = f2bf(acc[2]); o.w = f2bf(acc[3]);
        *(ushort4v*)&qkvI[(size_t)(node0 + 16 * g + l15) * RW + p * H_ +
                          c2 * 16 + q * 4] = o;
      }
    }
  }
}

// ---------------------------------------------------------------------------
// Phase 2: one WAVE per batch node, gathering from interleaved qkvI
// (768 B contiguous per neighbor). No LDS, no barriers.
// ---------------------------------------------------------------------------
__global__ __launch_bounds__(256) void agg_kernel(
    const int* __restrict__ nbr,
    const unsigned short* __restrict__ qkvI,
    float* __restrict__ out) {
  const int lane = threadIdx.x & 63;
  const int wv = threadIdx.x >> 6;
  const int b = blockIdx.x * 4 + wv;
  const int l15 = lane & 15;
  const int kg = lane >> 4;

  const int ni = nbr[b * K_ + (l15 < K_ ? l15 : 0)];
  const size_t nbase = (size_t)ni * RW;

  // scores[i][j] = q_i . k_j
  f32x4 sc = (f32x4)0.0f;
#pragma unroll
  for (int k = 0; k < 4; ++k) {
    const int off = k * 32 + kg * 8;
    bf16x8 qf = *(const bf16x8*)&qkvI[nbase + off];
    bf16x8 kf = *(const bf16x8*)&qkvI[nbase + H_ + off];
    sc = __builtin_amdgcn_mfma_f32_16x16x32_bf16(qf, kf, sc, 0, 0, 0);
  }

  if (l15 >= K_) {
#pragma unroll
    for (int r = 0; r < 4; ++r) sc[r] = -3.0e38f;
  }

  float mx[4], e[4], sm[4];
#pragma unroll
  for (int r = 0; r < 4; ++r) mx[r] = sc[r];
#pragma unroll
  for (int st = 1; st < 16; st <<= 1)
#pragma unroll
    for (int r = 0; r < 4; ++r) mx[r] = fmaxf(mx[r], __shfl_xor(mx[r], st, 16));
#pragma unroll
  for (int r = 0; r < 4; ++r) { e[r] = __expf(sc[r] - mx[r]); sm[r] = e[r]; }
#pragma unroll
  for (int st = 1; st < 16; st <<= 1)
#pragma unroll
    for (int r = 0; r < 4; ++r) sm[r] += __shfl_xor(sm[r], st, 16);

  float cs = 0.0f;
#pragma unroll
  for (int r = 0; r < 4; ++r) {
    float a = e[r] * __builtin_amdgcn_rcpf(sm[r]);
    if (kg * 4 + r >= K_) a = 0.0f;
    cs += a;
  }
  cs += __shfl_xor(cs, 16, 64);
  cs += __shfl_xor(cs, 32, 64);

  float o0 = 0.0f, o1 = 0.0f;
#pragma unroll
  for (int j = 0; j < K_; ++j) {
    const float cj = __shfl(cs, j, 64);
    const int nj = __shfl(ni, j, 64);
    const unsigned int v2 =
        *(const unsigned int*)&qkvI[(size_t)nj * RW + 2 * H_ + 2 * lane];
    o0 = fmaf(cj, bf2f(v2 & 0xffffu), o0);
    o1 = fmaf(cj, bf2f(v2 >> 16), o1);
  }
  *(float2*)&out[(size_t)b * H_ + 2 * lane] = make_float2(o0, o1);
}

extern "C" void kernel_launch(void* const* d_in, const int* in_sizes, int n_in,
                              void* d_out, int out_size, void* d_ws, size_t ws_size,
                              hipStream_t stream) {
  const int* nbr = (const int*)d_in[0];
  const float* E = (const float*)d_in[1];
  const float* W1a = (const float*)d_in[2];
  const float* W1b = (const float*)d_in[3];
  const float* W2a = (const float*)d_in[4];
  const float* W2b = (const float*)d_in[5];
  const float* W3a = (const float*)d_in[6];
  const float* W3b = (const float*)d_in[7];
  float* out = (float*)d_out;

  // workspace: qkvI [N][384] bf16 interleaved = 76.8 MB, then frag-major weights
  unsigned short* qkvI = (unsigned short*)d_ws;
  unsigned short* wat2 = qkvI + (size_t)N_ * RW;
  unsigned short* wbt2 = wat2 + (size_t)3 * 64 * 512;

  prep_kernel<<<(3 * 64 * 512 + 3 * 32 * 512) / 256, 256, 0, stream>>>(
      W1a, W1b, W2a, W2b, W3a, W3b, wat2, wbt2);
  const int waves = N_ / 32;                 // 3125
  proj_kernel<<<(waves + 3) / 4, 256, 0, stream>>>(E, wat2, wbt2, qkvI);
  agg_kernel<<<B_ / 4, 256, 0, stream>>>(nbr, qkvI, out);
}

// Round 6
// 251.384 us; speedup vs baseline: 1.4059x; 1.3503x over previous
//
#include <hip/hip_runtime.h>
#include <hip/hip_bf16.h>

// Problem constants (reference: B,K,N,F,H = 20000,10,100000,256,128)
constexpr int B_ = 20000;
constexpr int K_ = 10;
constexpr int N_ = 100000;
constexpr int F_ = 256;
constexpr int H_ = 128;
constexpr int RW = 3 * H_;  // interleaved qkv row width (384 ushorts = 768 B)

typedef __attribute__((ext_vector_type(8))) short bf16x8;
typedef __attribute__((ext_vector_type(4))) float f32x4;
typedef __attribute__((ext_vector_type(4))) unsigned short ushort4v;

__device__ __forceinline__ unsigned short f2bf(float x) {
  unsigned int u = __builtin_bit_cast(unsigned int, x);
  unsigned int r = u + 0x7fffu + ((u >> 16) & 1u);
  return (unsigned short)(r >> 16);
}

__device__ __forceinline__ float bf2f(unsigned int u16) {
  return __builtin_bit_cast(float, u16 << 16);
}

__device__ __forceinline__ float fast_tanh(float x) {
  float e = __expf(2.0f * x);
  return 1.0f - 2.0f * __builtin_amdgcn_rcpf(e + 1.0f);
}

// ---------------------------------------------------------------------------
// Prep: weights -> fragment-major bf16 layout (proven correct in round 5).
// wat2 chunks (p, ks∈8, c∈8), 512 bf16 each: elem(lane,j) = Wa_p[32ks+8(lane>>4)+j][16c+(lane&15)]
// wbt2 chunks (p, c2∈8, ks2∈4):              elem(lane,j) = Wb_p[32ks2+8(lane>>4)+j][16c2+(lane&15)]
// In proj, each A-fragment load is lane*16B contiguous (one coalesced 1KB load).
// ---------------------------------------------------------------------------
__global__ __launch_bounds__(256) void prep_kernel(
    const float* __restrict__ W1a, const float* __restrict__ W1b,
    const float* __restrict__ W2a, const float* __restrict__ W2b,
    const float* __restrict__ W3a, const float* __restrict__ W3b,
    unsigned short* __restrict__ wat2, unsigned short* __restrict__ wbt2) {
  const float* Wa[3] = {W1a, W2a, W3a};
  const float* Wb[3] = {W1b, W2b, W3b};
  int g = blockIdx.x * 256 + threadIdx.x;
  if (g < 3 * 64 * 512) {
    int chunk = g >> 9;
    int e = g & 511;
    int lane = e >> 3, j = e & 7;
    int c = chunk & 7;
    int ks = (chunk >> 3) & 7;
    int p = chunk >> 6;
    int k = 32 * ks + 8 * (lane >> 4) + j;
    int h = 16 * c + (lane & 15);
    wat2[g] = f2bf(Wa[p][k * H_ + h]);
  } else {
    int g2 = g - 3 * 64 * 512;
    int chunk = g2 >> 9;
    int e = g2 & 511;
    int lane = e >> 3, j = e & 7;
    int ks2 = chunk & 3;
    int c2 = (chunk >> 2) & 7;
    int p = chunk >> 5;
    int k = 32 * ks2 + 8 * (lane >> 4) + j;
    int h2 = 16 * c2 + (lane & 15);
    wbt2[g2] = f2bf(Wb[p][k * H_ + h2]);
  }
}

// ---------------------------------------------------------------------------
// Projections, transposed compute: U^T = Wa^T(A, frag-major global) x X^T(B,
// LDS b128 from [node][f] rows). tanh -> ds_write_b64 into ts[node][h]
// (the C->A transpose bounce) -> GEMM2: qkv^T = Wb^T x T^T, packed 8B stores.
// Block = 256 thr / 4 waves, MT=64 nodes; wave w owns h-tiles {2w,2w+1}.
// All global loads coalesced; LDS padded (no bank conflicts); 2 barriers/p.
// ---------------------------------------------------------------------------
constexpr int MT = 64;
constexpr int XS = F_ + 8;  // 264 shorts = 528 B row stride (2-way max, free)
constexpr int TS = H_ + 8;  // 136 shorts = 272 B row stride

__global__ __launch_bounds__(256) void proj_kernel(
    const float* __restrict__ E,
    const unsigned short* __restrict__ wat2,
    const unsigned short* __restrict__ wbt2,
    unsigned short* __restrict__ qkvI) {
  __shared__ unsigned short xs[MT * XS];  // 33.8 KB
  __shared__ unsigned short ts[MT * TS];  // 17.4 KB

  const int tid = threadIdx.x;
  const int lane = tid & 63;
  const int w = tid >> 6;
  const int l15 = lane & 15;
  const int q = lane >> 4;
  const int row0 = blockIdx.x * MT;

  // ---- stage X tile (fp32 -> bf16), coalesced; clamp OOB rows to N-1
  {
    const float4* Eg = (const float4*)E;
#pragma unroll
    for (int it = 0; it < 16; ++it) {
      int i = tid + 256 * it;
      int r = i >> 6;
      int c4 = i & 63;
      int row = row0 + r;
      if (row >= N_) row = N_ - 1;
      float4 v = Eg[(size_t)row * (F_ / 4) + c4];
      ushort4v o;
      o.x = f2bf(v.x); o.y = f2bf(v.y); o.z = f2bf(v.z); o.w = f2bf(v.w);
      *(ushort4v*)&xs[r * XS + c4 * 4] = o;
    }
  }
  __syncthreads();

  for (int p = 0; p < 3; ++p) {
    const unsigned short* __restrict__ wa = wat2 + p * (64 * 512);
    const unsigned short* __restrict__ wb = wbt2 + p * (32 * 512);

    // ---- layer 1: U^T tiles, K=256. acc[i][nt]: h-tile 2w+i, node-tile nt.
    f32x4 acc[2][4];
#pragma unroll
    for (int i = 0; i < 2; ++i)
#pragma unroll
      for (int nt = 0; nt < 4; ++nt) acc[i][nt] = (f32x4)0.0f;

#pragma unroll
    for (int ks = 0; ks < 8; ++ks) {
      bf16x8 af0 = *(const bf16x8*)&wa[(ks * 8 + 2 * w) * 512 + lane * 8];
      bf16x8 af1 = *(const bf16x8*)&wa[(ks * 8 + 2 * w + 1) * 512 + lane * 8];
#pragma unroll
      for (int nt = 0; nt < 4; ++nt) {
        bf16x8 bx = *(const bf16x8*)&xs[(16 * nt + l15) * XS + 32 * ks + 8 * q];
        acc[0][nt] = __builtin_amdgcn_mfma_f32_16x16x32_bf16(af0, bx, acc[0][nt], 0, 0, 0);
        acc[1][nt] = __builtin_amdgcn_mfma_f32_16x16x32_bf16(af1, bx, acc[1][nt], 0, 0, 0);
      }
    }

    // ---- tanh + pack -> ts[node][h] via 8B LDS writes (C->A transpose)
    __syncthreads();  // prior p's ts reads complete
#pragma unroll
    for (int i = 0; i < 2; ++i)
#pragma unroll
      for (int nt = 0; nt < 4; ++nt) {
        ushort4v o;
        o.x = f2bf(fast_tanh(acc[i][nt][0]));
        o.y = f2bf(fast_tanh(acc[i][nt][1]));
        o.z = f2bf(fast_tanh(acc[i][nt][2]));
        o.w = f2bf(fast_tanh(acc[i][nt][3]));
        // value (h = 16*(2w+i)+4q+r, node = 16nt+l15)
        *(ushort4v*)&ts[(16 * nt + l15) * TS + 16 * (2 * w + i) + 4 * q] = o;
      }
    __syncthreads();

    // ---- layer 2: qkv^T tiles, K=128
    f32x4 ac2[2][4];
#pragma unroll
    for (int i = 0; i < 2; ++i)
#pragma unroll
      for (int nt = 0; nt < 4; ++nt) ac2[i][nt] = (f32x4)0.0f;

#pragma unroll
    for (int ks2 = 0; ks2 < 4; ++ks2) {
      bf16x8 af0 = *(const bf16x8*)&wb[((2 * w) * 4 + ks2) * 512 + lane * 8];
      bf16x8 af1 = *(const bf16x8*)&wb[((2 * w + 1) * 4 + ks2) * 512 + lane * 8];
#pragma unroll
      for (int nt = 0; nt < 4; ++nt) {
        bf16x8 bt = *(const bf16x8*)&ts[(16 * nt + l15) * TS + 32 * ks2 + 8 * q];
        ac2[0][nt] = __builtin_amdgcn_mfma_f32_16x16x32_bf16(af0, bt, ac2[0][nt], 0, 0, 0);
        ac2[1][nt] = __builtin_amdgcn_mfma_f32_16x16x32_bf16(af1, bt, ac2[1][nt], 0, 0, 0);
      }
    }

    // ---- store qkv^T: col=node, rows h2 consecutive -> 8B contiguous stores
#pragma unroll
    for (int i = 0; i < 2; ++i)
#pragma unroll
      for (int nt = 0; nt < 4; ++nt) {
        int n = row0 + 16 * nt + l15;
        if (n < N_) {
          ushort4v o;
          o.x = f2bf(ac2[i][nt][0]);
          o.y = f2bf(ac2[i][nt][1]);
          o.z = f2bf(ac2[i][nt][2]);
          o.w = f2bf(ac2[i][nt][3]);
          *(ushort4v*)&qkvI[(size_t)n * RW + p * H_ + 16 * (2 * w + i) + 4 * q] = o;
        }
      }
  }
}

// ---------------------------------------------------------------------------
// Phase 2: one WAVE per batch node, gathering from interleaved qkvI
// (768 B contiguous per neighbor). No LDS, no barriers. (Unchanged from R5.)
// ---------------------------------------------------------------------------
__global__ __launch_bounds__(256) void agg_kernel(
    const int* __restrict__ nbr,
    const unsigned short* __restrict__ qkvI,
    float* __restrict__ out) {
  const int lane = threadIdx.x & 63;
  const int wv = threadIdx.x >> 6;
  const int b = blockIdx.x * 4 + wv;
  const int l15 = lane & 15;
  const int kg = lane >> 4;

  const int ni = nbr[b * K_ + (l15 < K_ ? l15 : 0)];
  const size_t nbase = (size_t)ni * RW;

  // scores[i][j] = q_i . k_j
  f32x4 sc = (f32x4)0.0f;
#pragma unroll
  for (int k = 0; k < 4; ++k) {
    const int off = k * 32 + kg * 8;
    bf16x8 qf = *(const bf16x8*)&qkvI[nbase + off];
    bf16x8 kf = *(const bf16x8*)&qkvI[nbase + H_ + off];
    sc = __builtin_amdgcn_mfma_f32_16x16x32_bf16(qf, kf, sc, 0, 0, 0);
  }

  if (l15 >= K_) {
#pragma unroll
    for (int r = 0; r < 4; ++r) sc[r] = -3.0e38f;
  }

  float mx[4], e[4], sm[4];
#pragma unroll
  for (int r = 0; r < 4; ++r) mx[r] = sc[r];
#pragma unroll
  for (int st = 1; st < 16; st <<= 1)
#pragma unroll
    for (int r = 0; r < 4; ++r) mx[r] = fmaxf(mx[r], __shfl_xor(mx[r], st, 16));
#pragma unroll
  for (int r = 0; r < 4; ++r) { e[r] = __expf(sc[r] - mx[r]); sm[r] = e[r]; }
#pragma unroll
  for (int st = 1; st < 16; st <<= 1)
#pragma unroll
    for (int r = 0; r < 4; ++r) sm[r] += __shfl_xor(sm[r], st, 16);

  float cs = 0.0f;
#pragma unroll
  for (int r = 0; r < 4; ++r) {
    float a = e[r] * __builtin_amdgcn_rcpf(sm[r]);
    if (kg * 4 + r >= K_) a = 0.0f;
    cs += a;
  }
  cs += __shfl_xor(cs, 16, 64);
  cs += __shfl_xor(cs, 32, 64);

  float o0 = 0.0f, o1 = 0.0f;
#pragma unroll
  for (int j = 0; j < K_; ++j) {
    const float cj = __shfl(cs, j, 64);
    const int nj = __shfl(ni, j, 64);
    const unsigned int v2 =
        *(const unsigned int*)&qkvI[(size_t)nj * RW + 2 * H_ + 2 * lane];
    o0 = fmaf(cj, bf2f(v2 & 0xffffu), o0);
    o1 = fmaf(cj, bf2f(v2 >> 16), o1);
  }
  *(float2*)&out[(size_t)b * H_ + 2 * lane] = make_float2(o0, o1);
}

extern "C" void kernel_launch(void* const* d_in, const int* in_sizes, int n_in,
                              void* d_out, int out_size, void* d_ws, size_t ws_size,
                              hipStream_t stream) {
  const int* nbr = (const int*)d_in[0];
  const float* E = (const float*)d_in[1];
  const float* W1a = (const float*)d_in[2];
  const float* W1b = (const float*)d_in[3];
  const float* W2a = (const float*)d_in[4];
  const float* W2b = (const float*)d_in[5];
  const float* W3a = (const float*)d_in[6];
  const float* W3b = (const float*)d_in[7];
  float* out = (float*)d_out;

  // workspace: qkvI [N][384] bf16 interleaved = 76.8 MB, then frag-major weights
  unsigned short* qkvI = (unsigned short*)d_ws;
  unsigned short* wat2 = qkvI + (size_t)N_ * RW;
  unsigned short* wbt2 = wat2 + (size_t)3 * 64 * 512;

  prep_kernel<<<(3 * 64 * 512 + 3 * 32 * 512) / 256, 256, 0, stream>>>(
      W1a, W1b, W2a, W2b, W3a, W3b, wat2, wbt2);
  proj_kernel<<<(N_ + MT - 1) / MT, 256, 0, stream>>>(E, wat2, wbt2, qkvI);
  agg_kernel<<<B_ / 4, 256, 0, stream>>>(nbr, qkvI, out);
}